// Round 1
// baseline (365.777 us; speedup 1.0000x reference)
//
#include <hip/hip_runtime.h>

// FrameWiseCrossAttention: kv_len==1 => softmax==1 => out = broadcast(y),
// y = (c @ Wv^T + bv) @ Wo^T + bo. x/Wq/Wk/bq/bk are mathematically unused.
// B=2, T=16, tpf=1560, N=24960, DIM=1024. M = B*T = 32 rows.
//
// Pipeline (2 dispatches, was 3):
//   1) gemm_thin: v[32,1024] = c @ Wv^T + bv            (unchanged)
//   2) gemm_bcast: each block computes a 64-col slice of y[bt,:] from v[bt,:]
//      (row-independent: y[r,:] depends only on v[r,:]) and broadcasts it to
//      390 output rows with non-temporal stores (keeps Wo L2-resident).

#define DIM     1024
#define K4      (DIM / 4)       // 256 float4 per row
#define MROWS   32              // B*T
#define TPF     1560
#define JSLICES 16              // col slices of 64 columns
#define RCH     4               // row chunks per frame-row
#define RPB     (TPF / RCH)     // 390 rows per block

typedef float fvec4 __attribute__((ext_vector_type(4)));

// C[32,1024] = A[32,1024] @ W[1024,1024]^T + bias.
// 512 blocks x 256 threads. Block b owns output columns j0=2b, 2b+1. Wave w
// owns rows r0=8w..8w+7. K lane-sliced: lane covers float4 indices
// {t*64 + lane, t=0..3} -> every load is a coalesced 1KB dwordx4.
__global__ __launch_bounds__(256) void gemm_thin(const float* __restrict__ A,
                                                 const float* __restrict__ W,
                                                 const float* __restrict__ bias,
                                                 float* __restrict__ C) {
    const int wave = threadIdx.x >> 6;
    const int lane = threadIdx.x & 63;
    const int j0   = blockIdx.x * 2;
    const int r0   = wave * 8;

    const fvec4* __restrict__ A4 = (const fvec4*)A;                       // row stride K4
    const fvec4* __restrict__ W0 = (const fvec4*)(W + (size_t)j0 * DIM);
    const fvec4* __restrict__ W1 = (const fvec4*)(W + (size_t)(j0 + 1) * DIM);

    fvec4 wa[4], wb[4];
#pragma unroll
    for (int t = 0; t < 4; ++t) {
        wa[t] = W0[t * 64 + lane];
        wb[t] = W1[t * 64 + lane];
    }

    float accA[8], accB[8];
#pragma unroll
    for (int r = 0; r < 8; ++r) { accA[r] = 0.f; accB[r] = 0.f; }

#pragma unroll
    for (int r = 0; r < 8; ++r) {
        const fvec4* __restrict__ Ar = A4 + (size_t)(r0 + r) * K4;
#pragma unroll
        for (int t = 0; t < 4; ++t) {
            fvec4 a = Ar[t * 64 + lane];
            accA[r] += a.x * wa[t].x + a.y * wa[t].y + a.z * wa[t].z + a.w * wa[t].w;
            accB[r] += a.x * wb[t].x + a.y * wb[t].y + a.z * wb[t].z + a.w * wb[t].w;
        }
    }

#pragma unroll
    for (int r = 0; r < 8; ++r) {
        float va = accA[r], vb = accB[r];
#pragma unroll
        for (int off = 32; off > 0; off >>= 1) {
            va += __shfl_down(va, off, 64);
            vb += __shfl_down(vb, off, 64);
        }
        accA[r] = va; accB[r] = vb;
    }

    if (lane == 0) {
        const float b0 = bias[j0], b1 = bias[j0 + 1];
#pragma unroll
        for (int r = 0; r < 8; ++r) {
            C[(size_t)(r0 + r) * DIM + j0]     = accA[r] + b0;
            C[(size_t)(r0 + r) * DIM + j0 + 1] = accB[r] + b1;
        }
    }
}

// Fused gemm2 + broadcast. 2048 blocks x 256 threads.
// blockIdx.x = (bt * RCH + rc) * JSLICES + jc  (jc fastest -> 16 consecutive
// blocks cover a full 1024-col row range: good DRAM locality).
// Phase A: wave w computes y cols jc*64 + w*16 + [0,16) from v[bt,:] with the
//          same K lane-slicing (bit-identical numerics to gemm_thin).
// Phase B: broadcast the 64-col slice to rows [bt*TPF + rc*390, +390) with
//          non-temporal dwordx4 stores (streaming writes bypass L2, so Wo
//          stays L2-resident across the R=4 redundant reads).
__global__ __launch_bounds__(256) void gemm_bcast(const float* __restrict__ V,
                                                  const float* __restrict__ Wo,
                                                  const float* __restrict__ bo,
                                                  float* __restrict__ out) {
    const int jc = blockIdx.x % JSLICES;
    const int rc = (blockIdx.x / JSLICES) % RCH;
    const int bt = blockIdx.x / (JSLICES * RCH);

    const int wave = threadIdx.x >> 6;
    const int lane = threadIdx.x & 63;
    const int jbase = jc * 64 + wave * 16;

    const fvec4* __restrict__ V4 = (const fvec4*)(V + (size_t)bt * DIM);

    fvec4 va[4];
#pragma unroll
    for (int t = 0; t < 4; ++t) va[t] = V4[t * 64 + lane];

    __shared__ float ys[64];  // y slice (cols jc*64 .. jc*64+63), bias included

    float acc[16];
#pragma unroll
    for (int cc = 0; cc < 16; ++cc) {
        const fvec4* __restrict__ Wr = (const fvec4*)(Wo + (size_t)(jbase + cc) * DIM);
        float s = 0.f;
#pragma unroll
        for (int t = 0; t < 4; ++t) {
            fvec4 w = Wr[t * 64 + lane];
            s += va[t].x * w.x + va[t].y * w.y + va[t].z * w.z + va[t].w * w.w;
        }
        acc[cc] = s;
    }

#pragma unroll
    for (int cc = 0; cc < 16; ++cc) {
        float s = acc[cc];
#pragma unroll
        for (int off = 32; off > 0; off >>= 1) s += __shfl_down(s, off, 64);
        if (lane == 0) ys[wave * 16 + cc] = s + bo[jbase + cc];
    }
    __syncthreads();

    // Broadcast. thread -> (f4 col within slice, row phase):
    const int fcol = threadIdx.x & 15;   // f4 index within the 64-col slice
    const int rof  = threadIdx.x >> 4;   // 0..15
    fvec4 val;
    val.x = ys[fcol * 4 + 0];
    val.y = ys[fcol * 4 + 1];
    val.z = ys[fcol * 4 + 2];
    val.w = ys[fcol * 4 + 3];

    fvec4* o = (fvec4*)out
             + ((size_t)bt * TPF + (size_t)rc * RPB) * K4
             + (size_t)jc * 16 + fcol;
    // rows r = rof + 16*i, i = 0..23 (384 rows) + tail of 6 rows
#pragma unroll
    for (int i = 0; i < 24; ++i) {
        __builtin_nontemporal_store(val, o + (size_t)(rof + 16 * i) * K4);
    }
    if (rof < 6) {
        __builtin_nontemporal_store(val, o + (size_t)(rof + 16 * 24) * K4);
    }
}

extern "C" void kernel_launch(void* const* d_in, const int* in_sizes, int n_in,
                              void* d_out, int out_size, void* d_ws, size_t ws_size,
                              hipStream_t stream) {
    // inputs: 0=x 1=c 2=Wq 3=bq 4=Wk 5=bk 6=Wv 7=bv 8=Wo 9=bo
    const float* c  = (const float*)d_in[1];
    const float* Wv = (const float*)d_in[6];
    const float* bv = (const float*)d_in[7];
    const float* Wo = (const float*)d_in[8];
    const float* bo = (const float*)d_in[9];
    float* out = (float*)d_out;

    float* v = (float*)d_ws;  // [32,1024]

    gemm_thin<<<DIM / 2, 256, 0, stream>>>(c, Wv, bv, v);
    gemm_bcast<<<MROWS * RCH * JSLICES, 256, 0, stream>>>(v, Wo, bo, out);
}

// Round 2
// 330.079 us; speedup vs baseline: 1.1082x; 1.1082x over previous
//
#include <hip/hip_runtime.h>
#include <hip/hip_bf16.h>

// FrameWiseCrossAttention: kv_len==1 => softmax==1 => out = broadcast(y),
// y = (c @ Wv^T + bv) @ Wo^T + bo. x/Wq/Wk/bq/bk are mathematically unused.
// B=2, T=16, tpf=1560, N=24960, DIM=1024. M = B*T = 32 rows.
//
// NOTE (R1 post-mortem): fusing gemm2 into the broadcast (64-col slices +
// nontemporal stores) regressed +36us: 256B-per-row strided writes from
// asynchronous blocks fragment the HBM write stream, and 512MB of redundant
// Wo reads serialize ahead of the stores. The broadcast's 4KB-contiguous
// per-row write runs are load-bearing. Keep the 3-kernel structure.

#define DIM    1024
#define K4     (DIM / 4)    // 256 float4 per row
#define MROWS  32           // B*T
#define TPF    1560
#define CHUNK  13
#define SPLITS 120          // 120 * 13 = 1560

typedef float fvec4 __attribute__((ext_vector_type(4)));

// C[32,1024] = A[32,1024] @ W[1024,1024]^T + bias.
// 512 blocks x 256 threads. Block b owns output columns j0=2b, 2b+1 (its 4
// waves share the two W rows -> L1 reuse). Wave w owns rows r0=8w..8w+7.
// K is lane-sliced: lane covers float4 indices {t*64 + lane, t=0..3} so every
// load instruction is a fully coalesced 1KB dwordx4. No LDS, no barriers.
__global__ __launch_bounds__(256) void gemm_thin(const float* __restrict__ A,
                                                 const float* __restrict__ W,
                                                 const float* __restrict__ bias,
                                                 float* __restrict__ C) {
    const int wave = threadIdx.x >> 6;
    const int lane = threadIdx.x & 63;
    const int j0   = blockIdx.x * 2;
    const int r0   = wave * 8;

    const fvec4* __restrict__ A4 = (const fvec4*)A;                       // row stride K4
    const fvec4* __restrict__ W0 = (const fvec4*)(W + (size_t)j0 * DIM);
    const fvec4* __restrict__ W1 = (const fvec4*)(W + (size_t)(j0 + 1) * DIM);

    fvec4 wa[4], wb[4];
#pragma unroll
    for (int t = 0; t < 4; ++t) {
        wa[t] = W0[t * 64 + lane];
        wb[t] = W1[t * 64 + lane];
    }

    float accA[8], accB[8];
#pragma unroll
    for (int r = 0; r < 8; ++r) { accA[r] = 0.f; accB[r] = 0.f; }

#pragma unroll
    for (int r = 0; r < 8; ++r) {
        const fvec4* __restrict__ Ar = A4 + (size_t)(r0 + r) * K4;
#pragma unroll
        for (int t = 0; t < 4; ++t) {
            fvec4 a = Ar[t * 64 + lane];
            accA[r] += a.x * wa[t].x + a.y * wa[t].y + a.z * wa[t].z + a.w * wa[t].w;
            accB[r] += a.x * wb[t].x + a.y * wb[t].y + a.z * wb[t].z + a.w * wb[t].w;
        }
    }

    // reduce across 64 lanes
#pragma unroll
    for (int r = 0; r < 8; ++r) {
        float va = accA[r], vb = accB[r];
#pragma unroll
        for (int off = 32; off > 0; off >>= 1) {
            va += __shfl_down(va, off, 64);
            vb += __shfl_down(vb, off, 64);
        }
        accA[r] = va; accB[r] = vb;
    }

    if (lane == 0) {
        const float b0 = bias[j0], b1 = bias[j0 + 1];
#pragma unroll
        for (int r = 0; r < 8; ++r) {
            C[(size_t)(r0 + r) * DIM + j0]     = accA[r] + b0;
            C[(size_t)(r0 + r) * DIM + j0 + 1] = accB[r] + b1;
        }
    }
}

// out[bt*TPF + p, :] = y[bt, :]. 3840 blocks x 256 threads, 13 rows each.
// Each row written as one 4KB contiguous run (256 threads x dwordx4) —
// this contiguity is what keeps the write stream at ~fill-rate BW.
__global__ __launch_bounds__(256) void bcast(const float* __restrict__ y,
                                             float* __restrict__ out) {
    const int bt = blockIdx.x / SPLITS;
    const int ch = blockIdx.x % SPLITS;

    const fvec4 val = ((const fvec4*)(y + (size_t)bt * DIM))[threadIdx.x];

    fvec4* o = (fvec4*)out + ((size_t)bt * TPF + (size_t)ch * CHUNK) * K4;
#pragma unroll
    for (int i = 0; i < CHUNK; ++i) {
        o[(size_t)i * K4 + threadIdx.x] = val;
    }
}

extern "C" void kernel_launch(void* const* d_in, const int* in_sizes, int n_in,
                              void* d_out, int out_size, void* d_ws, size_t ws_size,
                              hipStream_t stream) {
    // inputs: 0=x 1=c 2=Wq 3=bq 4=Wk 5=bk 6=Wv 7=bv 8=Wo 9=bo
    const float* c  = (const float*)d_in[1];
    const float* Wv = (const float*)d_in[6];
    const float* bv = (const float*)d_in[7];
    const float* Wo = (const float*)d_in[8];
    const float* bo = (const float*)d_in[9];
    float* out = (float*)d_out;

    float* v = (float*)d_ws;                  // [32,1024]
    float* y = (float*)d_ws + MROWS * DIM;    // [32,1024]

    gemm_thin<<<DIM / 2, 256, 0, stream>>>(c, Wv, bv, v);
    gemm_thin<<<DIM / 2, 256, 0, stream>>>(v, Wo, bo, y);
    bcast<<<MROWS * SPLITS, 256, 0, stream>>>(y, out);
}